// Round 1
// 545.197 us; speedup vs baseline: 2.6588x; 2.6588x over previous
//
#include <hip/hip_runtime.h>
#include <hip/hip_bf16.h>

// Problem constants
#define B_   16
#define SEQ  577
#define P_   576      // SEQ-1 patches
#define DM   768
#define NH   12
#define DK   64
#define TEMP 8.0f     // sqrt(64)
#define LNEPS 1e-6f
#define EPS_  1e-12f
#define MROWS (B_*SEQ) // 9232

typedef __attribute__((ext_vector_type(8))) short short8;   // 8 bf16 (4 VGPRs)
typedef __attribute__((ext_vector_type(4))) float f32x4;    // MFMA C/D

// ---- ws layout (BYTE offsets; all 16B-aligned) ----
// pen fp32 : 16*576*576*4            = 21,233,664
// qh  bf16 : 16*12*577*64*2          = 14,180,352
// kh  bf16 : 14,180,352
// vh  bf16 : 14,180,352
// vt  bf16 : 16*12*64*640*2          = 15,728,640   (V transposed, padded cols)
// Obf bf16 : 16*577*12*64*2          = 14,180,352   (attn out, row-major (9232,768))
// wt  bf16 : 4*768*768*2             =  4,718,592   (transposed weights: q,k,v,fc)
// rn  fp32 : 16*576*4                = 36,864
// fc  fp32 : aliases qh+kh (dead after attn), 28,360,704
// total 98,439,168 bytes (< previous 107.9 MB footprint)
static const size_t PEN_B = 0;
static const size_t QH_B  = 21233664;
static const size_t KH_B  = 35414016;
static const size_t VH_B  = 49594368;
static const size_t VT_B  = 63774720;
static const size_t OBF_B = 79503360;
static const size_t WT_B  = 93683712;
static const size_t RN_B  = 98402304;
static const size_t FC_B  = QH_B;

// ---- dtype-adaptive loads: detect bf16 vs fp32 from ln_gamma bit pattern ----
__device__ __forceinline__ bool bf_flag(const void* gamma) {
    return (((const unsigned int*)gamma)[0] & 0xFFFFu) != 0u;
}
__device__ __forceinline__ float ldf(const void* p, size_t i, bool bf) {
    if (bf) {
        unsigned int w = ((unsigned int)((const unsigned short*)p)[i]) << 16;
        return __uint_as_float(w);
    }
    return ((const float*)p)[i];
}
__device__ __forceinline__ unsigned short f2bu(float x) {
    __hip_bfloat16 h = __float2bfloat16(x);
    return *(unsigned short*)&h;
}

// ---------- row norms of patch embeddings (skip CLS row) ----------
__global__ __launch_bounds__(256) void k_rownorm(const void* __restrict__ emb,
                                                 const void* __restrict__ gamma,
                                                 float* __restrict__ rn) {
    bool bf = bf_flag(gamma);
    int row = blockIdx.x;
    int b = row / P_, i = row % P_;
    size_t base = ((size_t)(b * SEQ + 1 + i)) * DM;
    float s = 0.f;
    for (int c = threadIdx.x; c < DM; c += 256) { float v = ldf(emb, base + c, bf); s += v * v; }
    __shared__ float red[4];
    for (int off = 32; off > 0; off >>= 1) s += __shfl_down(s, off, 64);
    int lane = threadIdx.x & 63, w = threadIdx.x >> 6;
    if (lane == 0) red[w] = s;
    __syncthreads();
    if (threadIdx.x == 0) rn[row] = rsqrtf(red[0] + red[1] + red[2] + red[3] + EPS_);
}

// ---------- weight transpose+convert: W (k,n) fp32/bf16 -> WT (n,k) bf16 ----------
__global__ __launch_bounds__(256) void k_wt(const void* __restrict__ w0,
                                            const void* __restrict__ w1,
                                            const void* __restrict__ w2,
                                            const void* __restrict__ w3,
                                            const void* __restrict__ gamma,
                                            unsigned short* __restrict__ wt) {
    bool bf = bf_flag(gamma);
    int which = blockIdx.z;
    const void* W = which == 0 ? w0 : (which == 1 ? w1 : (which == 2 ? w2 : w3));
    unsigned short* WT = wt + (size_t)which * DM * DM;
    int k0 = blockIdx.y * 64, n0 = blockIdx.x * 64;
    __shared__ unsigned short Ts[64][69];
    int tid = threadIdx.x;
    {
        int kr = tid >> 2, nq = (tid & 3) * 16;
        size_t src = (size_t)(k0 + kr) * DM + n0 + nq;
        #pragma unroll
        for (int u = 0; u < 16; u++) Ts[kr][nq + u] = f2bu(ldf(W, src + u, bf));
    }
    __syncthreads();
    {
        int nr = tid >> 2, kq = (tid & 3) * 16;
        unsigned short tmp[16];
        #pragma unroll
        for (int u = 0; u < 16; u++) tmp[u] = Ts[kq + u][nr];
        uint4* dst = (uint4*)(WT + (size_t)(n0 + nr) * DM + k0 + kq);
        dst[0] = *(const uint4*)&tmp[0];
        dst[1] = *(const uint4*)&tmp[8];
    }
}

// ---------- penalty via MFMA: pen[b][i][j] = (e_i.e_j)*rn_i*rn_j*dist(i,j) ----------
// 64x64 tile, K=768, A = emb rows i, B = emb rows j (both [row][k] -> QK^T style)
__global__ __launch_bounds__(256) void k_penalty_mfma(const void* __restrict__ emb,
                                                      const void* __restrict__ pos,
                                                      const void* __restrict__ gamma,
                                                      const float* __restrict__ rn,
                                                      float* __restrict__ pen) {
    bool bf = bf_flag(gamma);
    int b = blockIdx.z;
    int i0 = blockIdx.y * 64, j0 = blockIdx.x * 64;
    __shared__ __align__(16) unsigned short As[64][72];
    __shared__ __align__(16) unsigned short Bs[64][72];
    int tid = threadIdx.x;
    int lane = tid & 63, w = tid >> 6;

    f32x4 acc[4];
    #pragma unroll
    for (int c = 0; c < 4; c++) acc[c] = (f32x4){0.f, 0.f, 0.f, 0.f};

    int srow = tid >> 2, sq = (tid & 3) * 16;
    size_t ebase = ((size_t)b * SEQ + 1) * DM;   // skip CLS
    size_t sa = ebase + (size_t)(i0 + srow) * DM + sq;
    size_t sb = ebase + (size_t)(j0 + srow) * DM + sq;

    for (int kc = 0; kc < DM; kc += 64) {
        if (bf) {
            const uint4* pa = (const uint4*)((const unsigned short*)emb + sa + kc);
            const uint4* pb = (const uint4*)((const unsigned short*)emb + sb + kc);
            *(uint4*)&As[srow][sq] = pa[0]; *(uint4*)&As[srow][sq + 8] = pa[1];
            *(uint4*)&Bs[srow][sq] = pb[0]; *(uint4*)&Bs[srow][sq + 8] = pb[1];
        } else {
            const float* pa = (const float*)emb + sa + kc;
            const float* pb = (const float*)emb + sb + kc;
            unsigned short ta[16], tb[16];
            #pragma unroll
            for (int u = 0; u < 4; u++) {
                float4 fa = ((const float4*)pa)[u];
                float4 fb = ((const float4*)pb)[u];
                ta[u*4+0] = f2bu(fa.x); ta[u*4+1] = f2bu(fa.y);
                ta[u*4+2] = f2bu(fa.z); ta[u*4+3] = f2bu(fa.w);
                tb[u*4+0] = f2bu(fb.x); tb[u*4+1] = f2bu(fb.y);
                tb[u*4+2] = f2bu(fb.z); tb[u*4+3] = f2bu(fb.w);
            }
            *(uint4*)&As[srow][sq] = *(const uint4*)&ta[0];
            *(uint4*)&As[srow][sq + 8] = *(const uint4*)&ta[8];
            *(uint4*)&Bs[srow][sq] = *(const uint4*)&tb[0];
            *(uint4*)&Bs[srow][sq + 8] = *(const uint4*)&tb[8];
        }
        __syncthreads();
        #pragma unroll
        for (int s = 0; s < 2; s++) {
            short8 af = *(const short8*)&As[w * 16 + (lane & 15)][s * 32 + (lane >> 4) * 8];
            #pragma unroll
            for (int c = 0; c < 4; c++) {
                short8 bfr = *(const short8*)&Bs[c * 16 + (lane & 15)][s * 32 + (lane >> 4) * 8];
                acc[c] = __builtin_amdgcn_mfma_f32_16x16x32_bf16(af, bfr, acc[c], 0, 0, 0);
            }
        }
        __syncthreads();
    }
    // epilogue: scale by rn_i*rn_j*dist
    size_t pbase = (size_t)b * P_ * 2;
    int rbase = (lane >> 4) * 4, cbase = lane & 15;
    float pix[4], piy[4], rni_[4], pjx[4], pjy[4], rnj_[4];
    #pragma unroll
    for (int jj = 0; jj < 4; jj++) {
        int i = i0 + w * 16 + rbase + jj;
        pix[jj] = ldf(pos, pbase + (size_t)i * 2, bf);
        piy[jj] = ldf(pos, pbase + (size_t)i * 2 + 1, bf);
        rni_[jj] = rn[b * P_ + i];
    }
    #pragma unroll
    for (int c = 0; c < 4; c++) {
        int j = j0 + c * 16 + cbase;
        pjx[c] = ldf(pos, pbase + (size_t)j * 2, bf);
        pjy[c] = ldf(pos, pbase + (size_t)j * 2 + 1, bf);
        rnj_[c] = rn[b * P_ + j];
    }
    float* pp = pen + (size_t)b * P_ * P_;
    #pragma unroll
    for (int c = 0; c < 4; c++)
        #pragma unroll
        for (int jj = 0; jj < 4; jj++) {
            int i = i0 + w * 16 + rbase + jj;
            int j = j0 + c * 16 + cbase;
            float dx = pix[jj] - pjx[c], dy = piy[jj] - pjy[c];
            pp[(size_t)i * P_ + j] = acc[c][jj] * rni_[jj] * rnj_[c] * sqrtf(dx * dx + dy * dy + EPS_);
        }
}

// ---------- qkv projection via MFMA: Y = X @ W, output bf16 head-split ----------
// 128x128 tile, BK=64, 4 waves in 2x2 quadrants. A: fp32->bf16 on the fly; B: WT bf16.
__global__ __launch_bounds__(256) void k_proj_mfma(const void* __restrict__ q,
                                                   const void* __restrict__ k,
                                                   const void* __restrict__ v,
                                                   const unsigned short* __restrict__ wt,
                                                   const void* __restrict__ gamma,
                                                   unsigned short* __restrict__ qh,
                                                   unsigned short* __restrict__ kh,
                                                   unsigned short* __restrict__ vh) {
    bool bf = bf_flag(gamma);
    int which = blockIdx.z;
    const void* X = which == 0 ? q : (which == 1 ? k : v);
    const unsigned short* WT = wt + (size_t)which * DM * DM;
    unsigned short* Y = which == 0 ? qh : (which == 1 ? kh : vh);
    float scale = which == 0 ? (1.0f / TEMP) : 1.0f;
    int m0 = blockIdx.x * 128, n0 = blockIdx.y * 128;

    __shared__ __align__(16) unsigned short As[128][72];
    __shared__ __align__(16) unsigned short Bs[128][72];
    int tid = threadIdx.x;
    int lane = tid & 63, w = tid >> 6;
    int wr = w >> 1, wc = w & 1;

    f32x4 acc[4][4];
    #pragma unroll
    for (int r = 0; r < 4; r++)
        #pragma unroll
        for (int c = 0; c < 4; c++) acc[r][c] = (f32x4){0.f, 0.f, 0.f, 0.f};

    int sr = tid >> 1, sh = (tid & 1) * 32;
    int gm_s = m0 + sr; if (gm_s >= MROWS) gm_s = MROWS - 1;  // clamp, stores guarded
    const size_t arow = (size_t)gm_s * DM;
    const size_t brow = (size_t)(n0 + sr) * DM;

    for (int kc = 0; kc < DM; kc += 64) {
        if (bf) {
            const uint4* src = (const uint4*)((const unsigned short*)X + arow + kc + sh);
            #pragma unroll
            for (int u = 0; u < 4; u++) *(uint4*)&As[sr][sh + u * 8] = src[u];
        } else {
            const float* src = (const float*)X + arow + kc + sh;
            unsigned short tmp[32];
            #pragma unroll
            for (int u = 0; u < 8; u++) {
                float4 f = ((const float4*)src)[u];
                tmp[u*4+0] = f2bu(f.x); tmp[u*4+1] = f2bu(f.y);
                tmp[u*4+2] = f2bu(f.z); tmp[u*4+3] = f2bu(f.w);
            }
            #pragma unroll
            for (int u = 0; u < 4; u++) *(uint4*)&As[sr][sh + u * 8] = *(const uint4*)&tmp[u * 8];
        }
        {
            const uint4* src = (const uint4*)(WT + brow + kc + sh);
            #pragma unroll
            for (int u = 0; u < 4; u++) *(uint4*)&Bs[sr][sh + u * 8] = src[u];
        }
        __syncthreads();
        #pragma unroll
        for (int s = 0; s < 2; s++) {
            short8 af[4], bfr[4];
            #pragma unroll
            for (int r = 0; r < 4; r++)
                af[r] = *(const short8*)&As[wr * 64 + r * 16 + (lane & 15)][s * 32 + (lane >> 4) * 8];
            #pragma unroll
            for (int c = 0; c < 4; c++)
                bfr[c] = *(const short8*)&Bs[wc * 64 + c * 16 + (lane & 15)][s * 32 + (lane >> 4) * 8];
            #pragma unroll
            for (int r = 0; r < 4; r++)
                #pragma unroll
                for (int c = 0; c < 4; c++)
                    acc[r][c] = __builtin_amdgcn_mfma_f32_16x16x32_bf16(af[r], bfr[c], acc[r][c], 0, 0, 0);
        }
        __syncthreads();
    }
    int rbase = (lane >> 4) * 4, cbase = lane & 15;
    #pragma unroll
    for (int r = 0; r < 4; r++) {
        #pragma unroll
        for (int jj = 0; jj < 4; jj++) {
            int gm = m0 + wr * 64 + r * 16 + rbase + jj;
            if (gm < MROWS) {
                int b = gm / SEQ, n = gm % SEQ;
                #pragma unroll
                for (int c = 0; c < 4; c++) {
                    int gc = n0 + wc * 64 + c * 16 + cbase;
                    int h = gc >> 6, d = gc & 63;
                    Y[(((size_t)(b * NH + h) * SEQ) + n) * DK + d] = f2bu(acc[r][c][jj] * scale);
                }
            }
        }
    }
}

// ---------- V transpose: vh (B,H,N,64) -> vt (B,H,64,640) ----------
__global__ __launch_bounds__(256) void k_vt(const unsigned short* __restrict__ vh,
                                            unsigned short* __restrict__ vt) {
    int ntile = blockIdx.x;       // 0..9
    int bh = blockIdx.y;          // 0..191
    __shared__ unsigned short Ts[64][72];
    int tid = threadIdx.x;
    int n0 = ntile * 64;
    {
        int r = tid >> 2, c = (tid & 3) * 16;
        int gn = n0 + r; if (gn > 576) gn = 576;
        const uint4* src = (const uint4*)(vh + ((size_t)bh * SEQ + gn) * DK + c);
        uint4 a = src[0], bv = src[1];
        *(uint4*)&Ts[r][c] = a; *(uint4*)&Ts[r][c + 8] = bv;
    }
    __syncthreads();
    {
        int d = tid >> 2, c = (tid & 3) * 16;
        unsigned short tmp[16];
        #pragma unroll
        for (int u = 0; u < 16; u++) tmp[u] = Ts[c + u][d];
        uint4* dst = (uint4*)(vt + ((size_t)bh * DK + d) * 640 + n0 + c);
        dst[0] = *(uint4*)&tmp[0];
        dst[1] = *(uint4*)&tmp[8];
    }
}

// ---------- flash attention: block = (b, h, 64-query tile), writes bf16 O ----------
__global__ __launch_bounds__(256) void k_attn2(const unsigned short* __restrict__ qh,
                                               const unsigned short* __restrict__ kh,
                                               const unsigned short* __restrict__ vt,
                                               const float* __restrict__ pen,
                                               unsigned short* __restrict__ O) {
    int it = blockIdx.x, h = blockIdx.y, b = blockIdx.z;
    int bh = b * NH + h;
    int i0 = it * 64;
    __shared__ unsigned short Qs[64][72], Ks[64][72], Vs[64][72], Ps[64][72];
    int tid = threadIdx.x;
    int lane = tid & 63, w = tid >> 6;

    {
        int r = tid >> 2, c = (tid & 3) * 16;
        int gi = i0 + r; if (gi > 576) gi = 576;
        const uint4* src = (const uint4*)(qh + ((size_t)bh * SEQ + gi) * DK + c);
        uint4 a = src[0], bv = src[1];
        *(uint4*)&Qs[r][c] = a; *(uint4*)&Qs[r][c + 8] = bv;
    }
    __syncthreads();
    short8 qfrag[2];
    #pragma unroll
    for (int s = 0; s < 2; s++)
        qfrag[s] = *(const short8*)&Qs[w * 16 + (lane & 15)][s * 32 + (lane >> 4) * 8];

    f32x4 o_acc[4];
    #pragma unroll
    for (int i = 0; i < 4; i++) o_acc[i] = (f32x4){0.f, 0.f, 0.f, 0.f};
    float m_run[4], l_run[4];
    #pragma unroll
    for (int r = 0; r < 4; r++) { m_run[r] = -1e30f; l_run[r] = 0.f; }

    const float* penb = pen + (size_t)b * P_ * P_;
    int colbase = lane & 15;
    int rloc = (lane >> 4) * 4;

    for (int kt = 0; kt < 10; kt++) {
        int j0 = kt * 64;
        {
            int r = tid >> 2, c = (tid & 3) * 16;
            int gj = j0 + r; if (gj > 576) gj = 576;
            const uint4* src = (const uint4*)(kh + ((size_t)bh * SEQ + gj) * DK + c);
            uint4 a = src[0], bv = src[1];
            *(uint4*)&Ks[r][c] = a; *(uint4*)&Ks[r][c + 8] = bv;
            const uint4* vsrc = (const uint4*)(vt + ((size_t)bh * DK + r) * 640 + j0 + c);
            uint4 va = vsrc[0], vb = vsrc[1];
            *(uint4*)&Vs[r][c] = va; *(uint4*)&Vs[r][c + 8] = vb;
        }
        __syncthreads();

        f32x4 sfrag[4];
        #pragma unroll
        for (int nt = 0; nt < 4; nt++) {
            f32x4 acc = (f32x4){0.f, 0.f, 0.f, 0.f};
            #pragma unroll
            for (int s = 0; s < 2; s++) {
                short8 bfrag = *(const short8*)&Ks[nt * 16 + colbase][s * 32 + (lane >> 4) * 8];
                acc = __builtin_amdgcn_mfma_f32_16x16x32_bf16(qfrag[s], bfrag, acc, 0, 0, 0);
            }
            sfrag[nt] = acc;
        }
        #pragma unroll
        for (int nt = 0; nt < 4; nt++) {
            int j = j0 + nt * 16 + colbase;
            #pragma unroll
            for (int rg = 0; rg < 4; rg++) {
                int i = i0 + w * 16 + rloc + rg;
                float sv = sfrag[nt][rg];
                if (i >= 1 && i <= 576 && j >= 1 && j <= 576)
                    sv -= penb[(size_t)(i - 1) * P_ + (j - 1)];
                if (j > 576) sv = -1e30f;
                sfrag[nt][rg] = sv;
            }
        }
        float alpha[4];
        #pragma unroll
        for (int rg = 0; rg < 4; rg++) {
            float t = fmaxf(fmaxf(sfrag[0][rg], sfrag[1][rg]),
                            fmaxf(sfrag[2][rg], sfrag[3][rg]));
            #pragma unroll
            for (int off = 1; off < 16; off <<= 1) t = fmaxf(t, __shfl_xor(t, off, 64));
            float mn = fmaxf(m_run[rg], t);
            alpha[rg] = __expf(m_run[rg] - mn);
            m_run[rg] = mn;
        }
        float rsum[4] = {0.f, 0.f, 0.f, 0.f};
        #pragma unroll
        for (int nt = 0; nt < 4; nt++) {
            #pragma unroll
            for (int rg = 0; rg < 4; rg++) {
                float p = __expf(sfrag[nt][rg] - m_run[rg]);
                rsum[rg] += p;
                Ps[w * 16 + rloc + rg][nt * 16 + colbase] = f2bu(p);
            }
        }
        #pragma unroll
        for (int rg = 0; rg < 4; rg++) {
            float t = rsum[rg];
            #pragma unroll
            for (int off = 1; off < 16; off <<= 1) t += __shfl_xor(t, off, 64);
            l_run[rg] = l_run[rg] * alpha[rg] + t;
        }
        #pragma unroll
        for (int nt = 0; nt < 4; nt++)
            #pragma unroll
            for (int rg = 0; rg < 4; rg++) o_acc[nt][rg] *= alpha[rg];

        #pragma unroll
        for (int s = 0; s < 2; s++) {
            short8 afrag = *(const short8*)&Ps[w * 16 + (lane & 15)][s * 32 + (lane >> 4) * 8];
            #pragma unroll
            for (int nt = 0; nt < 4; nt++) {
                short8 bfrag = *(const short8*)&Vs[nt * 16 + colbase][s * 32 + (lane >> 4) * 8];
                o_acc[nt] = __builtin_amdgcn_mfma_f32_16x16x32_bf16(afrag, bfrag, o_acc[nt], 0, 0, 0);
            }
        }
        __syncthreads();
    }
    // normalize + store bf16 (O layout: (b, n, h, d) == row-major (9232, 768))
    #pragma unroll
    for (int rg = 0; rg < 4; rg++) {
        int i = i0 + w * 16 + rloc + rg;
        if (i < SEQ) {
            float linv = 1.0f / l_run[rg];
            #pragma unroll
            for (int nt = 0; nt < 4; nt++) {
                int d = nt * 16 + colbase;
                O[(((size_t)(b * SEQ + i)) * NH + h) * DK + d] = f2bu(o_acc[nt][rg] * linv);
            }
        }
    }
}

// ---------- out projection via MFMA + residual: fc = Obf @ wfc + q ----------
__global__ __launch_bounds__(256) void k_fc_mfma(const unsigned short* __restrict__ Obf,
                                                 const unsigned short* __restrict__ wtfc,
                                                 const void* __restrict__ qin,
                                                 const void* __restrict__ gamma,
                                                 float* __restrict__ fcout) {
    bool bf = bf_flag(gamma);
    int m0 = blockIdx.x * 128, n0 = blockIdx.y * 128;
    __shared__ __align__(16) unsigned short As[128][72];
    __shared__ __align__(16) unsigned short Bs[128][72];
    int tid = threadIdx.x;
    int lane = tid & 63, w = tid >> 6;
    int wr = w >> 1, wc = w & 1;

    f32x4 acc[4][4];
    #pragma unroll
    for (int r = 0; r < 4; r++)
        #pragma unroll
        for (int c = 0; c < 4; c++) acc[r][c] = (f32x4){0.f, 0.f, 0.f, 0.f};

    int sr = tid >> 1, sh = (tid & 1) * 32;
    int gm_s = m0 + sr; if (gm_s >= MROWS) gm_s = MROWS - 1;
    const size_t arow = (size_t)gm_s * DM;
    const size_t brow = (size_t)(n0 + sr) * DM;

    for (int kc = 0; kc < DM; kc += 64) {
        {
            const uint4* src = (const uint4*)(Obf + arow + kc + sh);
            #pragma unroll
            for (int u = 0; u < 4; u++) *(uint4*)&As[sr][sh + u * 8] = src[u];
        }
        {
            const uint4* src = (const uint4*)(wtfc + brow + kc + sh);
            #pragma unroll
            for (int u = 0; u < 4; u++) *(uint4*)&Bs[sr][sh + u * 8] = src[u];
        }
        __syncthreads();
        #pragma unroll
        for (int s = 0; s < 2; s++) {
            short8 af[4], bfr[4];
            #pragma unroll
            for (int r = 0; r < 4; r++)
                af[r] = *(const short8*)&As[wr * 64 + r * 16 + (lane & 15)][s * 32 + (lane >> 4) * 8];
            #pragma unroll
            for (int c = 0; c < 4; c++)
                bfr[c] = *(const short8*)&Bs[wc * 64 + c * 16 + (lane & 15)][s * 32 + (lane >> 4) * 8];
            #pragma unroll
            for (int r = 0; r < 4; r++)
                #pragma unroll
                for (int c = 0; c < 4; c++)
                    acc[r][c] = __builtin_amdgcn_mfma_f32_16x16x32_bf16(af[r], bfr[c], acc[r][c], 0, 0, 0);
        }
        __syncthreads();
    }
    int rbase = (lane >> 4) * 4, cbase = lane & 15;
    #pragma unroll
    for (int r = 0; r < 4; r++) {
        #pragma unroll
        for (int jj = 0; jj < 4; jj++) {
            int gm = m0 + wr * 64 + r * 16 + rbase + jj;
            if (gm < MROWS) {
                #pragma unroll
                for (int c = 0; c < 4; c++) {
                    int gc = n0 + wc * 64 + c * 16 + cbase;
                    fcout[(size_t)gm * DM + gc] = acc[r][c][jj] + ldf(qin, (size_t)gm * DM + gc, bf);
                }
            }
        }
    }
}

// ---------- layernorm (dtype-adaptive output) ----------
__global__ __launch_bounds__(256) void k_ln(const float* __restrict__ x,
                                            const void* __restrict__ gamma,
                                            const void* __restrict__ beta,
                                            void* __restrict__ out) {
    bool bf = bf_flag(gamma);
    int row = blockIdx.x;
    const float* xr = x + (size_t)row * DM;
    int tid = threadIdx.x;
    float v[3];
    float ssum = 0.f;
    #pragma unroll
    for (int u = 0; u < 3; u++) { v[u] = xr[tid + u * 256]; ssum += v[u]; }
    __shared__ float red[4];
    __shared__ float mu_s, var_s;
    float t = ssum;
    for (int off = 32; off > 0; off >>= 1) t += __shfl_down(t, off, 64);
    int lane = tid & 63, w = tid >> 6;
    if (lane == 0) red[w] = t;
    __syncthreads();
    if (tid == 0) mu_s = (red[0] + red[1] + red[2] + red[3]) * (1.0f / DM);
    __syncthreads();
    float mu = mu_s;
    float vs = 0.f;
    #pragma unroll
    for (int u = 0; u < 3; u++) { float d = v[u] - mu; vs += d * d; }
    t = vs;
    for (int off = 32; off > 0; off >>= 1) t += __shfl_down(t, off, 64);
    if (lane == 0) red[w] = t;
    __syncthreads();
    if (tid == 0) var_s = (red[0] + red[1] + red[2] + red[3]) * (1.0f / DM);
    __syncthreads();
    float rstd = rsqrtf(var_s + LNEPS);
    #pragma unroll
    for (int u = 0; u < 3; u++) {
        int c = tid + u * 256;
        float val = (v[u] - mu) * rstd * ldf(gamma, c, bf) + ldf(beta, c, bf);
        size_t idx = (size_t)row * DM + c;
        if (bf) ((__hip_bfloat16*)out)[idx] = __float2bfloat16(val);
        else    ((float*)out)[idx] = val;
    }
}

extern "C" void kernel_launch(void* const* d_in, const int* in_sizes, int n_in,
                              void* d_out, int out_size, void* d_ws, size_t ws_size,
                              hipStream_t stream) {
    const void* q   = d_in[0];
    const void* k   = d_in[1];
    const void* v   = d_in[2];
    const void* pos = d_in[3];
    const void* pe  = d_in[4];
    const void* wq  = d_in[5];
    const void* wk  = d_in[6];
    const void* wv  = d_in[7];
    const void* wfc = d_in[8];
    const void* gam = d_in[9];
    const void* bet = d_in[10];
    char* wsb = (char*)d_ws;
    float*          pen = (float*)(wsb + PEN_B);
    unsigned short* qh  = (unsigned short*)(wsb + QH_B);
    unsigned short* kh  = (unsigned short*)(wsb + KH_B);
    unsigned short* vh  = (unsigned short*)(wsb + VH_B);
    unsigned short* vt  = (unsigned short*)(wsb + VT_B);
    unsigned short* Obf = (unsigned short*)(wsb + OBF_B);
    unsigned short* wt  = (unsigned short*)(wsb + WT_B);
    float*          rn  = (float*)(wsb + RN_B);
    float*          fc  = (float*)(wsb + FC_B);

    k_wt<<<dim3(12, 12, 4), 256, 0, stream>>>(wq, wk, wv, wfc, gam, wt);
    k_rownorm<<<B_ * P_, 256, 0, stream>>>(pe, gam, rn);
    k_penalty_mfma<<<dim3(9, 9, B_), 256, 0, stream>>>(pe, pos, gam, rn, pen);
    k_proj_mfma<<<dim3(73, 6, 3), 256, 0, stream>>>(q, k, v, wt, gam, qh, kh, vh);
    k_vt<<<dim3(10, 192), 256, 0, stream>>>(vh, vt);
    k_attn2<<<dim3(10, NH, B_), 256, 0, stream>>>(qh, kh, vt, pen, Obf);
    k_fc_mfma<<<dim3(73, 6), 256, 0, stream>>>(Obf, wt + (size_t)3 * DM * DM, q, gam, fc);
    k_ln<<<MROWS, 256, 0, stream>>>(fc, gam, bet, d_out);
}

// Round 2
// 448.408 us; speedup vs baseline: 3.2327x; 1.2158x over previous
//
#include <hip/hip_runtime.h>
#include <hip/hip_bf16.h>

// Problem constants
#define B_   16
#define SEQ  577
#define P_   576      // SEQ-1 patches
#define DM   768
#define NH   12
#define DK   64
#define TEMP 8.0f     // sqrt(64)
#define LNEPS 1e-6f
#define EPS_  1e-12f
#define MROWS (B_*SEQ) // 9232

typedef __attribute__((ext_vector_type(8))) short short8;   // 8 bf16 (4 VGPRs)
typedef __attribute__((ext_vector_type(4))) float f32x4;    // MFMA C/D

// ---- ws layout (BYTE offsets; all 16B-aligned) ----
static const size_t PEN_B = 0;
static const size_t QH_B  = 21233664;
static const size_t KH_B  = 35414016;
static const size_t VH_B  = 49594368;
static const size_t VT_B  = 63774720;
static const size_t OBF_B = 79503360;
static const size_t WT_B  = 93683712;
static const size_t RN_B  = 98402304;
static const size_t FC_B  = QH_B;

// ---- dtype-adaptive loads: detect bf16 vs fp32 from ln_gamma bit pattern ----
__device__ __forceinline__ bool bf_flag(const void* gamma) {
    return (((const unsigned int*)gamma)[0] & 0xFFFFu) != 0u;
}
__device__ __forceinline__ float ldf(const void* p, size_t i, bool bf) {
    if (bf) {
        unsigned int w = ((unsigned int)((const unsigned short*)p)[i]) << 16;
        return __uint_as_float(w);
    }
    return ((const float*)p)[i];
}
__device__ __forceinline__ unsigned short f2bu(float x) {
    __hip_bfloat16 h = __float2bfloat16(x);
    return *(unsigned short*)&h;
}

// ---------- row norms of patch embeddings (skip CLS row) ----------
__global__ __launch_bounds__(256) void k_rownorm(const void* __restrict__ emb,
                                                 const void* __restrict__ gamma,
                                                 float* __restrict__ rn) {
    bool bf = bf_flag(gamma);
    int row = blockIdx.x;
    int b = row / P_, i = row % P_;
    size_t base = ((size_t)(b * SEQ + 1 + i)) * DM;
    float s = 0.f;
    for (int c = threadIdx.x; c < DM; c += 256) { float v = ldf(emb, base + c, bf); s += v * v; }
    __shared__ float red[4];
    for (int off = 32; off > 0; off >>= 1) s += __shfl_down(s, off, 64);
    int lane = threadIdx.x & 63, w = threadIdx.x >> 6;
    if (lane == 0) red[w] = s;
    __syncthreads();
    if (threadIdx.x == 0) rn[row] = rsqrtf(red[0] + red[1] + red[2] + red[3] + EPS_);
}

// ---------- weight transpose+convert: W (k,n) fp32/bf16 -> WT (n,k) bf16 ----------
__global__ __launch_bounds__(256) void k_wt(const void* __restrict__ w0,
                                            const void* __restrict__ w1,
                                            const void* __restrict__ w2,
                                            const void* __restrict__ w3,
                                            const void* __restrict__ gamma,
                                            unsigned short* __restrict__ wt) {
    bool bf = bf_flag(gamma);
    int which = blockIdx.z;
    const void* W = which == 0 ? w0 : (which == 1 ? w1 : (which == 2 ? w2 : w3));
    unsigned short* WT = wt + (size_t)which * DM * DM;
    int k0 = blockIdx.y * 64, n0 = blockIdx.x * 64;
    __shared__ unsigned short Ts[64][69];
    int tid = threadIdx.x;
    {
        int kr = tid >> 2, nq = (tid & 3) * 16;
        size_t src = (size_t)(k0 + kr) * DM + n0 + nq;
        #pragma unroll
        for (int u = 0; u < 16; u++) Ts[kr][nq + u] = f2bu(ldf(W, src + u, bf));
    }
    __syncthreads();
    {
        int nr = tid >> 2, kq = (tid & 3) * 16;
        unsigned short tmp[16];
        #pragma unroll
        for (int u = 0; u < 16; u++) tmp[u] = Ts[kq + u][nr];
        uint4* dst = (uint4*)(WT + (size_t)(n0 + nr) * DM + k0 + kq);
        dst[0] = *(const uint4*)&tmp[0];
        dst[1] = *(const uint4*)&tmp[8];
    }
}

// ---------- penalty via MFMA: pen[b][i][j] = (e_i.e_j)*rn_i*rn_j*dist(i,j) ----------
__global__ __launch_bounds__(256) void k_penalty_mfma(const void* __restrict__ emb,
                                                      const void* __restrict__ pos,
                                                      const void* __restrict__ gamma,
                                                      const float* __restrict__ rn,
                                                      float* __restrict__ pen) {
    bool bf = bf_flag(gamma);
    int b = blockIdx.z;
    int i0 = blockIdx.y * 64, j0 = blockIdx.x * 64;
    __shared__ __align__(16) unsigned short As[64][72];
    __shared__ __align__(16) unsigned short Bs[64][72];
    int tid = threadIdx.x;
    int lane = tid & 63, w = tid >> 6;

    f32x4 acc[4];
    #pragma unroll
    for (int c = 0; c < 4; c++) acc[c] = (f32x4){0.f, 0.f, 0.f, 0.f};

    int srow = tid >> 2, sq = (tid & 3) * 16;
    size_t ebase = ((size_t)b * SEQ + 1) * DM;   // skip CLS
    size_t sa = ebase + (size_t)(i0 + srow) * DM + sq;
    size_t sb = ebase + (size_t)(j0 + srow) * DM + sq;

    for (int kc = 0; kc < DM; kc += 64) {
        if (bf) {
            const uint4* pa = (const uint4*)((const unsigned short*)emb + sa + kc);
            const uint4* pb = (const uint4*)((const unsigned short*)emb + sb + kc);
            *(uint4*)&As[srow][sq] = pa[0]; *(uint4*)&As[srow][sq + 8] = pa[1];
            *(uint4*)&Bs[srow][sq] = pb[0]; *(uint4*)&Bs[srow][sq + 8] = pb[1];
        } else {
            const float* pa = (const float*)emb + sa + kc;
            const float* pb = (const float*)emb + sb + kc;
            unsigned short ta[16], tb[16];
            #pragma unroll
            for (int u = 0; u < 4; u++) {
                float4 fa = ((const float4*)pa)[u];
                float4 fb = ((const float4*)pb)[u];
                ta[u*4+0] = f2bu(fa.x); ta[u*4+1] = f2bu(fa.y);
                ta[u*4+2] = f2bu(fa.z); ta[u*4+3] = f2bu(fa.w);
                tb[u*4+0] = f2bu(fb.x); tb[u*4+1] = f2bu(fb.y);
                tb[u*4+2] = f2bu(fb.z); tb[u*4+3] = f2bu(fb.w);
            }
            *(uint4*)&As[srow][sq] = *(const uint4*)&ta[0];
            *(uint4*)&As[srow][sq + 8] = *(const uint4*)&ta[8];
            *(uint4*)&Bs[srow][sq] = *(const uint4*)&tb[0];
            *(uint4*)&Bs[srow][sq + 8] = *(const uint4*)&tb[8];
        }
        __syncthreads();
        #pragma unroll
        for (int s = 0; s < 2; s++) {
            short8 af = *(const short8*)&As[w * 16 + (lane & 15)][s * 32 + (lane >> 4) * 8];
            #pragma unroll
            for (int c = 0; c < 4; c++) {
                short8 bfr = *(const short8*)&Bs[c * 16 + (lane & 15)][s * 32 + (lane >> 4) * 8];
                acc[c] = __builtin_amdgcn_mfma_f32_16x16x32_bf16(af, bfr, acc[c], 0, 0, 0);
            }
        }
        __syncthreads();
    }
    size_t pbase = (size_t)b * P_ * 2;
    int rbase = (lane >> 4) * 4, cbase = lane & 15;
    float pix[4], piy[4], rni_[4], pjx[4], pjy[4], rnj_[4];
    #pragma unroll
    for (int jj = 0; jj < 4; jj++) {
        int i = i0 + w * 16 + rbase + jj;
        pix[jj] = ldf(pos, pbase + (size_t)i * 2, bf);
        piy[jj] = ldf(pos, pbase + (size_t)i * 2 + 1, bf);
        rni_[jj] = rn[b * P_ + i];
    }
    #pragma unroll
    for (int c = 0; c < 4; c++) {
        int j = j0 + c * 16 + cbase;
        pjx[c] = ldf(pos, pbase + (size_t)j * 2, bf);
        pjy[c] = ldf(pos, pbase + (size_t)j * 2 + 1, bf);
        rnj_[c] = rn[b * P_ + j];
    }
    float* pp = pen + (size_t)b * P_ * P_;
    #pragma unroll
    for (int c = 0; c < 4; c++)
        #pragma unroll
        for (int jj = 0; jj < 4; jj++) {
            int i = i0 + w * 16 + rbase + jj;
            int j = j0 + c * 16 + cbase;
            float dx = pix[jj] - pjx[c], dy = piy[jj] - pjy[c];
            pp[(size_t)i * P_ + j] = acc[c][jj] * rni_[jj] * rnj_[c] * sqrtf(dx * dx + dy * dy + EPS_);
        }
}

// ---------- qkv projection via MFMA: Y = X @ W, output bf16 head-split ----------
__global__ __launch_bounds__(256) void k_proj_mfma(const void* __restrict__ q,
                                                   const void* __restrict__ k,
                                                   const void* __restrict__ v,
                                                   const unsigned short* __restrict__ wt,
                                                   const void* __restrict__ gamma,
                                                   unsigned short* __restrict__ qh,
                                                   unsigned short* __restrict__ kh,
                                                   unsigned short* __restrict__ vh) {
    bool bf = bf_flag(gamma);
    int which = blockIdx.z;
    const void* X = which == 0 ? q : (which == 1 ? k : v);
    const unsigned short* WT = wt + (size_t)which * DM * DM;
    unsigned short* Y = which == 0 ? qh : (which == 1 ? kh : vh);
    float scale = which == 0 ? (1.0f / TEMP) : 1.0f;
    int m0 = blockIdx.x * 128, n0 = blockIdx.y * 128;

    __shared__ __align__(16) unsigned short As[128][72];
    __shared__ __align__(16) unsigned short Bs[128][72];
    int tid = threadIdx.x;
    int lane = tid & 63, w = tid >> 6;
    int wr = w >> 1, wc = w & 1;

    f32x4 acc[4][4];
    #pragma unroll
    for (int r = 0; r < 4; r++)
        #pragma unroll
        for (int c = 0; c < 4; c++) acc[r][c] = (f32x4){0.f, 0.f, 0.f, 0.f};

    int sr = tid >> 1, sh = (tid & 1) * 32;
    int gm_s = m0 + sr; if (gm_s >= MROWS) gm_s = MROWS - 1;  // clamp, stores guarded
    const size_t arow = (size_t)gm_s * DM;
    const size_t brow = (size_t)(n0 + sr) * DM;

    for (int kc = 0; kc < DM; kc += 64) {
        if (bf) {
            const uint4* src = (const uint4*)((const unsigned short*)X + arow + kc + sh);
            #pragma unroll
            for (int u = 0; u < 4; u++) *(uint4*)&As[sr][sh + u * 8] = src[u];
        } else {
            const float* src = (const float*)X + arow + kc + sh;
            unsigned short tmp[32];
            #pragma unroll
            for (int u = 0; u < 8; u++) {
                float4 f = ((const float4*)src)[u];
                tmp[u*4+0] = f2bu(f.x); tmp[u*4+1] = f2bu(f.y);
                tmp[u*4+2] = f2bu(f.z); tmp[u*4+3] = f2bu(f.w);
            }
            #pragma unroll
            for (int u = 0; u < 4; u++) *(uint4*)&As[sr][sh + u * 8] = *(const uint4*)&tmp[u * 8];
        }
        {
            const uint4* src = (const uint4*)(WT + brow + kc + sh);
            #pragma unroll
            for (int u = 0; u < 4; u++) *(uint4*)&Bs[sr][sh + u * 8] = src[u];
        }
        __syncthreads();
        #pragma unroll
        for (int s = 0; s < 2; s++) {
            short8 af[4], bfr[4];
            #pragma unroll
            for (int r = 0; r < 4; r++)
                af[r] = *(const short8*)&As[wr * 64 + r * 16 + (lane & 15)][s * 32 + (lane >> 4) * 8];
            #pragma unroll
            for (int c = 0; c < 4; c++)
                bfr[c] = *(const short8*)&Bs[wc * 64 + c * 16 + (lane & 15)][s * 32 + (lane >> 4) * 8];
            #pragma unroll
            for (int r = 0; r < 4; r++)
                #pragma unroll
                for (int c = 0; c < 4; c++)
                    acc[r][c] = __builtin_amdgcn_mfma_f32_16x16x32_bf16(af[r], bfr[c], acc[r][c], 0, 0, 0);
        }
        __syncthreads();
    }
    int rbase = (lane >> 4) * 4, cbase = lane & 15;
    #pragma unroll
    for (int r = 0; r < 4; r++) {
        #pragma unroll
        for (int jj = 0; jj < 4; jj++) {
            int gm = m0 + wr * 64 + r * 16 + rbase + jj;
            if (gm < MROWS) {
                int b = gm / SEQ, n = gm % SEQ;
                #pragma unroll
                for (int c = 0; c < 4; c++) {
                    int gc = n0 + wc * 64 + c * 16 + cbase;
                    int h = gc >> 6, d = gc & 63;
                    Y[(((size_t)(b * NH + h) * SEQ) + n) * DK + d] = f2bu(acc[r][c][jj] * scale);
                }
            }
        }
    }
}

// ---------- V transpose: vh (B,H,N,64) -> vt (B,H,64,640) ----------
__global__ __launch_bounds__(256) void k_vt(const unsigned short* __restrict__ vh,
                                            unsigned short* __restrict__ vt) {
    int ntile = blockIdx.x;       // 0..9
    int bh = blockIdx.y;          // 0..191
    __shared__ unsigned short Ts[64][72];
    int tid = threadIdx.x;
    int n0 = ntile * 64;
    {
        int r = tid >> 2, c = (tid & 3) * 16;
        int gn = n0 + r; if (gn > 576) gn = 576;
        const uint4* src = (const uint4*)(vh + ((size_t)bh * SEQ + gn) * DK + c);
        uint4 a = src[0], bv = src[1];
        *(uint4*)&Ts[r][c] = a; *(uint4*)&Ts[r][c + 8] = bv;
    }
    __syncthreads();
    {
        int d = tid >> 2, c = (tid & 3) * 16;
        unsigned short tmp[16];
        #pragma unroll
        for (int u = 0; u < 16; u++) tmp[u] = Ts[c + u][d];
        uint4* dst = (uint4*)(vt + ((size_t)bh * DK + d) * 640 + n0 + c);
        dst[0] = *(uint4*)&tmp[0];
        dst[1] = *(uint4*)&tmp[8];
    }
}

// ---------- flash attention: 512 threads, QBLK=128, 8 waves of 16-row strips ----------
__global__ __launch_bounds__(512, 4) void k_attn2(const unsigned short* __restrict__ qh,
                                                  const unsigned short* __restrict__ kh,
                                                  const unsigned short* __restrict__ vt,
                                                  const float* __restrict__ pen,
                                                  unsigned short* __restrict__ O) {
    // XCD-aware bijective swizzle (960 blocks, 960 % 8 == 0)
    const int NWG = 5 * NH * B_;               // 960
    int flat = blockIdx.x + 5 * (blockIdx.y + NH * blockIdx.z);
    int id = (flat & 7) * (NWG >> 3) + (flat >> 3);
    int it = id % 5; int t2 = id / 5;
    int h = t2 % NH;  int b = t2 / NH;
    int bh = b * NH + h;
    int i0 = it * 128;

    __shared__ __align__(16) unsigned short Qs[128][72];
    __shared__ __align__(16) unsigned short Ks[64][72];
    __shared__ __align__(16) unsigned short Vs[64][72];
    __shared__ __align__(16) unsigned short Ps[128][72];
    int tid = threadIdx.x;
    int lane = tid & 63, w = tid >> 6;          // 8 waves

    // stage Q tile (128 rows, clamp OOB)
    {
        int r = tid >> 2, c = (tid & 3) * 16;
        int gi = i0 + r; if (gi > 576) gi = 576;
        const uint4* src = (const uint4*)(qh + ((size_t)bh * SEQ + gi) * DK + c);
        uint4 a = src[0], bv = src[1];
        *(uint4*)&Qs[r][c] = a; *(uint4*)&Qs[r][c + 8] = bv;
    }
    __syncthreads();
    short8 qfrag[2];
    #pragma unroll
    for (int s = 0; s < 2; s++)
        qfrag[s] = *(const short8*)&Qs[w * 16 + (lane & 15)][s * 32 + (lane >> 4) * 8];

    f32x4 o_acc[4];
    #pragma unroll
    for (int i = 0; i < 4; i++) o_acc[i] = (f32x4){0.f, 0.f, 0.f, 0.f};
    float m_run[4], l_run[4];
    #pragma unroll
    for (int r = 0; r < 4; r++) { m_run[r] = -1e30f; l_run[r] = 0.f; }

    const float* penb = pen + (size_t)b * P_ * P_;
    int colbase = lane & 15;
    int rloc = (lane >> 4) * 4;

    // per-row validity + clamped pen row pointers (loop-invariant)
    const float* prow[4]; bool iok[4];
    #pragma unroll
    for (int rg = 0; rg < 4; rg++) {
        int i = i0 + w * 16 + rloc + rg;
        int ii = i < 1 ? 1 : (i > 576 ? 576 : i);
        prow[rg] = penb + (size_t)(ii - 1) * P_;
        iok[rg] = (i >= 1 && i <= 576);
    }

    for (int kt = 0; kt < 10; kt++) {
        int j0 = kt * 64;
        // stage K tile (64x64) and V tile (64 dims x 64 keys); 1 uint4 each per thread
        {
            int r = tid >> 3, c = (tid & 7) * 8;
            int gj = j0 + r; if (gj > 576) gj = 576;
            *(uint4*)&Ks[r][c] = *(const uint4*)(kh + ((size_t)bh * SEQ + gj) * DK + c);
            *(uint4*)&Vs[r][c] = *(const uint4*)(vt + ((size_t)bh * DK + r) * 640 + j0 + c);
        }
        __syncthreads();

        // prefetch penalty (independent of S) — loads overlap the MFMAs below
        float pf[4][4];
        #pragma unroll
        for (int rg = 0; rg < 4; rg++) {
            #pragma unroll
            for (int nt = 0; nt < 4; nt++) {
                int j = j0 + nt * 16 + colbase;
                int jj = j < 1 ? 1 : (j > 576 ? 576 : j);
                float pv = prow[rg][jj - 1];
                pf[rg][nt] = (iok[rg] && j >= 1 && j <= 576) ? pv : 0.f;
            }
        }

        // S = Q K^T (wave strip: 16 rows x 64 keys)
        f32x4 sfrag[4];
        __builtin_amdgcn_s_setprio(1);
        #pragma unroll
        for (int nt = 0; nt < 4; nt++) {
            f32x4 acc = (f32x4){0.f, 0.f, 0.f, 0.f};
            #pragma unroll
            for (int s = 0; s < 2; s++) {
                short8 bfrag = *(const short8*)&Ks[nt * 16 + colbase][s * 32 + (lane >> 4) * 8];
                acc = __builtin_amdgcn_mfma_f32_16x16x32_bf16(qfrag[s], bfrag, acc, 0, 0, 0);
            }
            sfrag[nt] = acc;
        }
        __builtin_amdgcn_s_setprio(0);

        // apply penalty + key mask
        #pragma unroll
        for (int nt = 0; nt < 4; nt++) {
            int j = j0 + nt * 16 + colbase;
            #pragma unroll
            for (int rg = 0; rg < 4; rg++) {
                float sv = sfrag[nt][rg] - pf[rg][nt];
                if (j > 576) sv = -1e30f;
                sfrag[nt][rg] = sv;
            }
        }
        // online softmax (rows live across 16 lanes of each quad-group)
        float alpha[4];
        #pragma unroll
        for (int rg = 0; rg < 4; rg++) {
            float t = fmaxf(fmaxf(sfrag[0][rg], sfrag[1][rg]),
                            fmaxf(sfrag[2][rg], sfrag[3][rg]));
            #pragma unroll
            for (int off = 1; off < 16; off <<= 1) t = fmaxf(t, __shfl_xor(t, off, 64));
            float mn = fmaxf(m_run[rg], t);
            alpha[rg] = __expf(m_run[rg] - mn);
            m_run[rg] = mn;
        }
        float rsum[4] = {0.f, 0.f, 0.f, 0.f};
        #pragma unroll
        for (int nt = 0; nt < 4; nt++) {
            #pragma unroll
            for (int rg = 0; rg < 4; rg++) {
                float p = __expf(sfrag[nt][rg] - m_run[rg]);
                rsum[rg] += p;
                Ps[w * 16 + rloc + rg][nt * 16 + colbase] = f2bu(p);
            }
        }
        #pragma unroll
        for (int rg = 0; rg < 4; rg++) {
            float t = rsum[rg];
            #pragma unroll
            for (int off = 1; off < 16; off <<= 1) t += __shfl_xor(t, off, 64);
            l_run[rg] = l_run[rg] * alpha[rg] + t;
        }
        #pragma unroll
        for (int nt = 0; nt < 4; nt++)
            #pragma unroll
            for (int rg = 0; rg < 4; rg++) o_acc[nt][rg] *= alpha[rg];

        // O += P V
        __builtin_amdgcn_s_setprio(1);
        #pragma unroll
        for (int s = 0; s < 2; s++) {
            short8 afrag = *(const short8*)&Ps[w * 16 + (lane & 15)][s * 32 + (lane >> 4) * 8];
            #pragma unroll
            for (int nt = 0; nt < 4; nt++) {
                short8 bfrag = *(const short8*)&Vs[nt * 16 + colbase][s * 32 + (lane >> 4) * 8];
                o_acc[nt] = __builtin_amdgcn_mfma_f32_16x16x32_bf16(afrag, bfrag, o_acc[nt], 0, 0, 0);
            }
        }
        __builtin_amdgcn_s_setprio(0);
        __syncthreads();
    }
    // normalize + store bf16 (O layout: (b, n, h, d) == row-major (9232, 768))
    #pragma unroll
    for (int rg = 0; rg < 4; rg++) {
        int i = i0 + w * 16 + rloc + rg;
        if (i < SEQ) {
            float linv = 1.0f / l_run[rg];
            #pragma unroll
            for (int nt = 0; nt < 4; nt++) {
                int d = nt * 16 + colbase;
                O[(((size_t)(b * SEQ + i)) * NH + h) * DK + d] = f2bu(o_acc[nt][rg] * linv);
            }
        }
    }
}

// ---------- out projection via MFMA + residual: fc = Obf @ wfc + q ----------
__global__ __launch_bounds__(256) void k_fc_mfma(const unsigned short* __restrict__ Obf,
                                                 const unsigned short* __restrict__ wtfc,
                                                 const void* __restrict__ qin,
                                                 const void* __restrict__ gamma,
                                                 float* __restrict__ fcout) {
    bool bf = bf_flag(gamma);
    int m0 = blockIdx.x * 128, n0 = blockIdx.y * 128;
    __shared__ __align__(16) unsigned short As[128][72];
    __shared__ __align__(16) unsigned short Bs[128][72];
    int tid = threadIdx.x;
    int lane = tid & 63, w = tid >> 6;
    int wr = w >> 1, wc = w & 1;

    f32x4 acc[4][4];
    #pragma unroll
    for (int r = 0; r < 4; r++)
        #pragma unroll
        for (int c = 0; c < 4; c++) acc[r][c] = (f32x4){0.f, 0.f, 0.f, 0.f};

    int sr = tid >> 1, sh = (tid & 1) * 32;
    int gm_s = m0 + sr; if (gm_s >= MROWS) gm_s = MROWS - 1;
    const size_t arow = (size_t)gm_s * DM;
    const size_t brow = (size_t)(n0 + sr) * DM;

    for (int kc = 0; kc < DM; kc += 64) {
        {
            const uint4* src = (const uint4*)(Obf + arow + kc + sh);
            #pragma unroll
            for (int u = 0; u < 4; u++) *(uint4*)&As[sr][sh + u * 8] = src[u];
        }
        {
            const uint4* src = (const uint4*)(wtfc + brow + kc + sh);
            #pragma unroll
            for (int u = 0; u < 4; u++) *(uint4*)&Bs[sr][sh + u * 8] = src[u];
        }
        __syncthreads();
        #pragma unroll
        for (int s = 0; s < 2; s++) {
            short8 af[4], bfr[4];
            #pragma unroll
            for (int r = 0; r < 4; r++)
                af[r] = *(const short8*)&As[wr * 64 + r * 16 + (lane & 15)][s * 32 + (lane >> 4) * 8];
            #pragma unroll
            for (int c = 0; c < 4; c++)
                bfr[c] = *(const short8*)&Bs[wc * 64 + c * 16 + (lane & 15)][s * 32 + (lane >> 4) * 8];
            #pragma unroll
            for (int r = 0; r < 4; r++)
                #pragma unroll
                for (int c = 0; c < 4; c++)
                    acc[r][c] = __builtin_amdgcn_mfma_f32_16x16x32_bf16(af[r], bfr[c], acc[r][c], 0, 0, 0);
        }
        __syncthreads();
    }
    int rbase = (lane >> 4) * 4, cbase = lane & 15;
    #pragma unroll
    for (int r = 0; r < 4; r++) {
        #pragma unroll
        for (int jj = 0; jj < 4; jj++) {
            int gm = m0 + wr * 64 + r * 16 + rbase + jj;
            if (gm < MROWS) {
                #pragma unroll
                for (int c = 0; c < 4; c++) {
                    int gc = n0 + wc * 64 + c * 16 + cbase;
                    fcout[(size_t)gm * DM + gc] = acc[r][c][jj] + ldf(qin, (size_t)gm * DM + gc, bf);
                }
            }
        }
    }
}

// ---------- layernorm (dtype-adaptive output) ----------
__global__ __launch_bounds__(256) void k_ln(const float* __restrict__ x,
                                            const void* __restrict__ gamma,
                                            const void* __restrict__ beta,
                                            void* __restrict__ out) {
    bool bf = bf_flag(gamma);
    int row = blockIdx.x;
    const float* xr = x + (size_t)row * DM;
    int tid = threadIdx.x;
    float v[3];
    float ssum = 0.f;
    #pragma unroll
    for (int u = 0; u < 3; u++) { v[u] = xr[tid + u * 256]; ssum += v[u]; }
    __shared__ float red[4];
    __shared__ float mu_s, var_s;
    float t = ssum;
    for (int off = 32; off > 0; off >>= 1) t += __shfl_down(t, off, 64);
    int lane = tid & 63, w = tid >> 6;
    if (lane == 0) red[w] = t;
    __syncthreads();
    if (tid == 0) mu_s = (red[0] + red[1] + red[2] + red[3]) * (1.0f / DM);
    __syncthreads();
    float mu = mu_s;
    float vs = 0.f;
    #pragma unroll
    for (int u = 0; u < 3; u++) { float d = v[u] - mu; vs += d * d; }
    t = vs;
    for (int off = 32; off > 0; off >>= 1) t += __shfl_down(t, off, 64);
    if (lane == 0) red[w] = t;
    __syncthreads();
    if (tid == 0) var_s = (red[0] + red[1] + red[2] + red[3]) * (1.0f / DM);
    __syncthreads();
    float rstd = rsqrtf(var_s + LNEPS);
    #pragma unroll
    for (int u = 0; u < 3; u++) {
        int c = tid + u * 256;
        float val = (v[u] - mu) * rstd * ldf(gamma, c, bf) + ldf(beta, c, bf);
        size_t idx = (size_t)row * DM + c;
        if (bf) ((__hip_bfloat16*)out)[idx] = __float2bfloat16(val);
        else    ((float*)out)[idx] = val;
    }
}

extern "C" void kernel_launch(void* const* d_in, const int* in_sizes, int n_in,
                              void* d_out, int out_size, void* d_ws, size_t ws_size,
                              hipStream_t stream) {
    const void* q   = d_in[0];
    const void* k   = d_in[1];
    const void* v   = d_in[2];
    const void* pos = d_in[3];
    const void* pe  = d_in[4];
    const void* wq  = d_in[5];
    const void* wk  = d_in[6];
    const void* wv  = d_in[7];
    const void* wfc = d_in[8];
    const void* gam = d_in[9];
    const void* bet = d_in[10];
    char* wsb = (char*)d_ws;
    float*          pen = (float*)(wsb + PEN_B);
    unsigned short* qh  = (unsigned short*)(wsb + QH_B);
    unsigned short* kh  = (unsigned short*)(wsb + KH_B);
    unsigned short* vh  = (unsigned short*)(wsb + VH_B);
    unsigned short* vt  = (unsigned short*)(wsb + VT_B);
    unsigned short* Obf = (unsigned short*)(wsb + OBF_B);
    unsigned short* wt  = (unsigned short*)(wsb + WT_B);
    float*          rn  = (float*)(wsb + RN_B);
    float*          fc  = (float*)(wsb + FC_B);

    k_wt<<<dim3(12, 12, 4), 256, 0, stream>>>(wq, wk, wv, wfc, gam, wt);
    k_rownorm<<<B_ * P_, 256, 0, stream>>>(pe, gam, rn);
    k_penalty_mfma<<<dim3(9, 9, B_), 256, 0, stream>>>(pe, pos, gam, rn, pen);
    k_proj_mfma<<<dim3(73, 6, 3), 256, 0, stream>>>(q, k, v, wt, gam, qh, kh, vh);
    k_vt<<<dim3(10, 192), 256, 0, stream>>>(vh, vt);
    k_attn2<<<dim3(5, NH, B_), 512, 0, stream>>>(qh, kh, vt, pen, Obf);
    k_fc_mfma<<<dim3(73, 6), 256, 0, stream>>>(Obf, wt + (size_t)3 * DM * DM, q, gam, fc);
    k_ln<<<MROWS, 256, 0, stream>>>(fc, gam, bet, d_out);
}

// Round 3
// 438.523 us; speedup vs baseline: 3.3056x; 1.0225x over previous
//
#include <hip/hip_runtime.h>
#include <hip/hip_bf16.h>

// Problem constants
#define B_   16
#define SEQ  577
#define P_   576      // SEQ-1 patches
#define DM   768
#define NH   12
#define DK   64
#define TEMP 8.0f     // sqrt(64)
#define LNEPS 1e-6f
#define EPS_  1e-12f
#define MROWS (B_*SEQ) // 9232

typedef __attribute__((ext_vector_type(8))) short short8;   // 8 bf16 (4 VGPRs)
typedef __attribute__((ext_vector_type(4))) float f32x4;    // MFMA C/D

// ---- ws layout (BYTE offsets; all 16B-aligned) ----
static const size_t PEN_B = 0;
static const size_t QH_B  = 21233664;
static const size_t KH_B  = 35414016;
static const size_t VH_B  = 49594368;
static const size_t VT_B  = 63774720;
static const size_t OBF_B = 79503360;
static const size_t WT_B  = 93683712;
static const size_t RN_B  = 98402304;
static const size_t FC_B  = QH_B;

// ---- dtype-adaptive loads: detect bf16 vs fp32 from ln_gamma bit pattern ----
__device__ __forceinline__ bool bf_flag(const void* gamma) {
    return (((const unsigned int*)gamma)[0] & 0xFFFFu) != 0u;
}
__device__ __forceinline__ float ldf(const void* p, size_t i, bool bf) {
    if (bf) {
        unsigned int w = ((unsigned int)((const unsigned short*)p)[i]) << 16;
        return __uint_as_float(w);
    }
    return ((const float*)p)[i];
}
__device__ __forceinline__ unsigned short f2bu(float x) {
    __hip_bfloat16 h = __float2bfloat16(x);
    return *(unsigned short*)&h;
}

// ---- bijective XCD chunk swizzle (m204): maps launch index -> serial index so
// that each XCD's round-robin share is a CONTIGUOUS serial chunk.
__device__ __forceinline__ int xcd_chunk(int orig, int nwg) {
    int q = nwg >> 3, r = nwg & 7;
    int xcd = orig & 7, slot = orig >> 3;
    int base = xcd < r ? xcd * (q + 1) : r * (q + 1) + (xcd - r) * q;
    return base + slot;
}

// ---------- row norms of patch embeddings (skip CLS row) ----------
__global__ __launch_bounds__(256) void k_rownorm(const void* __restrict__ emb,
                                                 const void* __restrict__ gamma,
                                                 float* __restrict__ rn) {
    bool bf = bf_flag(gamma);
    int row = blockIdx.x;
    int b = row / P_, i = row % P_;
    size_t base = ((size_t)(b * SEQ + 1 + i)) * DM;
    float s = 0.f;
    for (int c = threadIdx.x; c < DM; c += 256) { float v = ldf(emb, base + c, bf); s += v * v; }
    __shared__ float red[4];
    for (int off = 32; off > 0; off >>= 1) s += __shfl_down(s, off, 64);
    int lane = threadIdx.x & 63, w = threadIdx.x >> 6;
    if (lane == 0) red[w] = s;
    __syncthreads();
    if (threadIdx.x == 0) rn[row] = rsqrtf(red[0] + red[1] + red[2] + red[3] + EPS_);
}

// ---------- weight transpose+convert: W (k,n) fp32/bf16 -> WT (n,k) bf16 ----------
__global__ __launch_bounds__(256) void k_wt(const void* __restrict__ w0,
                                            const void* __restrict__ w1,
                                            const void* __restrict__ w2,
                                            const void* __restrict__ w3,
                                            const void* __restrict__ gamma,
                                            unsigned short* __restrict__ wt) {
    bool bf = bf_flag(gamma);
    int which = blockIdx.z;
    const void* W = which == 0 ? w0 : (which == 1 ? w1 : (which == 2 ? w2 : w3));
    unsigned short* WT = wt + (size_t)which * DM * DM;
    int k0 = blockIdx.y * 64, n0 = blockIdx.x * 64;
    __shared__ unsigned short Ts[64][69];
    int tid = threadIdx.x;
    {
        int kr = tid >> 2, nq = (tid & 3) * 16;
        size_t src = (size_t)(k0 + kr) * DM + n0 + nq;
        #pragma unroll
        for (int u = 0; u < 16; u++) Ts[kr][nq + u] = f2bu(ldf(W, src + u, bf));
    }
    __syncthreads();
    {
        int nr = tid >> 2, kq = (tid & 3) * 16;
        unsigned short tmp[16];
        #pragma unroll
        for (int u = 0; u < 16; u++) tmp[u] = Ts[kq + u][nr];
        uint4* dst = (uint4*)(WT + (size_t)(n0 + nr) * DM + k0 + kq);
        dst[0] = *(const uint4*)&tmp[0];
        dst[1] = *(const uint4*)&tmp[8];
    }
}

// ---------- penalty via MFMA: pen[b][i][j] = (e_i.e_j)*rn_i*rn_j*dist(i,j) ----------
// 1-D grid 1296, serial = (b, i-tile, j-tile) with j innermost; XCD-chunked so
// each XCD owns 2 whole batches -> emb[b] slab (1.77 MB) is L2-resident.
__global__ __launch_bounds__(256) void k_penalty_mfma(const void* __restrict__ emb,
                                                      const void* __restrict__ pos,
                                                      const void* __restrict__ gamma,
                                                      const float* __restrict__ rn,
                                                      float* __restrict__ pen) {
    bool bf = bf_flag(gamma);
    int p = xcd_chunk(blockIdx.x, 9 * 9 * B_);
    int b = p / 81; int rem = p % 81;
    int i0 = (rem / 9) * 64, j0 = (rem % 9) * 64;
    __shared__ __align__(16) unsigned short As[64][72];
    __shared__ __align__(16) unsigned short Bs[64][72];
    int tid = threadIdx.x;
    int lane = tid & 63, w = tid >> 6;

    f32x4 acc[4];
    #pragma unroll
    for (int c = 0; c < 4; c++) acc[c] = (f32x4){0.f, 0.f, 0.f, 0.f};

    int srow = tid >> 2, sq = (tid & 3) * 16;
    size_t ebase = ((size_t)b * SEQ + 1) * DM;   // skip CLS
    size_t sa = ebase + (size_t)(i0 + srow) * DM + sq;
    size_t sb = ebase + (size_t)(j0 + srow) * DM + sq;

    for (int kc = 0; kc < DM; kc += 64) {
        if (bf) {
            const uint4* pa = (const uint4*)((const unsigned short*)emb + sa + kc);
            const uint4* pb = (const uint4*)((const unsigned short*)emb + sb + kc);
            *(uint4*)&As[srow][sq] = pa[0]; *(uint4*)&As[srow][sq + 8] = pa[1];
            *(uint4*)&Bs[srow][sq] = pb[0]; *(uint4*)&Bs[srow][sq + 8] = pb[1];
        } else {
            const float* pa = (const float*)emb + sa + kc;
            const float* pb = (const float*)emb + sb + kc;
            unsigned short ta[16], tb[16];
            #pragma unroll
            for (int u = 0; u < 4; u++) {
                float4 fa = ((const float4*)pa)[u];
                float4 fb = ((const float4*)pb)[u];
                ta[u*4+0] = f2bu(fa.x); ta[u*4+1] = f2bu(fa.y);
                ta[u*4+2] = f2bu(fa.z); ta[u*4+3] = f2bu(fa.w);
                tb[u*4+0] = f2bu(fb.x); tb[u*4+1] = f2bu(fb.y);
                tb[u*4+2] = f2bu(fb.z); tb[u*4+3] = f2bu(fb.w);
            }
            *(uint4*)&As[srow][sq] = *(const uint4*)&ta[0];
            *(uint4*)&As[srow][sq + 8] = *(const uint4*)&ta[8];
            *(uint4*)&Bs[srow][sq] = *(const uint4*)&tb[0];
            *(uint4*)&Bs[srow][sq + 8] = *(const uint4*)&tb[8];
        }
        __syncthreads();
        #pragma unroll
        for (int s = 0; s < 2; s++) {
            short8 af = *(const short8*)&As[w * 16 + (lane & 15)][s * 32 + (lane >> 4) * 8];
            #pragma unroll
            for (int c = 0; c < 4; c++) {
                short8 bfr = *(const short8*)&Bs[c * 16 + (lane & 15)][s * 32 + (lane >> 4) * 8];
                acc[c] = __builtin_amdgcn_mfma_f32_16x16x32_bf16(af, bfr, acc[c], 0, 0, 0);
            }
        }
        __syncthreads();
    }
    size_t pbase = (size_t)b * P_ * 2;
    int rbase = (lane >> 4) * 4, cbase = lane & 15;
    float pix[4], piy[4], rni_[4], pjx[4], pjy[4], rnj_[4];
    #pragma unroll
    for (int jj = 0; jj < 4; jj++) {
        int i = i0 + w * 16 + rbase + jj;
        pix[jj] = ldf(pos, pbase + (size_t)i * 2, bf);
        piy[jj] = ldf(pos, pbase + (size_t)i * 2 + 1, bf);
        rni_[jj] = rn[b * P_ + i];
    }
    #pragma unroll
    for (int c = 0; c < 4; c++) {
        int j = j0 + c * 16 + cbase;
        pjx[c] = ldf(pos, pbase + (size_t)j * 2, bf);
        pjy[c] = ldf(pos, pbase + (size_t)j * 2 + 1, bf);
        rnj_[c] = rn[b * P_ + j];
    }
    float* pp = pen + (size_t)b * P_ * P_;
    #pragma unroll
    for (int c = 0; c < 4; c++)
        #pragma unroll
        for (int jj = 0; jj < 4; jj++) {
            int i = i0 + w * 16 + rbase + jj;
            int j = j0 + c * 16 + cbase;
            float dx = pix[jj] - pjx[c], dy = piy[jj] - pjy[c];
            pp[(size_t)i * P_ + j] = acc[c][jj] * rni_[jj] * rnj_[c] * sqrtf(dx * dx + dy * dy + EPS_);
        }
}

// ---------- qkv projection via MFMA: Y = X @ W, output bf16 head-split ----------
// 1-D grid 1314, serial = (which, m, n) with n innermost; XCD-chunked so the 6
// n-tile blocks sharing one 393 KB X slab run adjacently on one XCD (L2 hit).
__global__ __launch_bounds__(256) void k_proj_mfma(const void* __restrict__ q,
                                                   const void* __restrict__ k,
                                                   const void* __restrict__ v,
                                                   const unsigned short* __restrict__ wt,
                                                   const void* __restrict__ gamma,
                                                   unsigned short* __restrict__ qh,
                                                   unsigned short* __restrict__ kh,
                                                   unsigned short* __restrict__ vh) {
    bool bf = bf_flag(gamma);
    int p = xcd_chunk(blockIdx.x, 73 * 6 * 3);
    int which = p / (73 * 6);
    int rem = p % (73 * 6);
    int m0 = (rem / 6) * 128, n0 = (rem % 6) * 128;
    const void* X = which == 0 ? q : (which == 1 ? k : v);
    const unsigned short* WT = wt + (size_t)which * DM * DM;
    unsigned short* Y = which == 0 ? qh : (which == 1 ? kh : vh);
    float scale = which == 0 ? (1.0f / TEMP) : 1.0f;

    __shared__ __align__(16) unsigned short As[128][72];
    __shared__ __align__(16) unsigned short Bs[128][72];
    int tid = threadIdx.x;
    int lane = tid & 63, w = tid >> 6;
    int wr = w >> 1, wc = w & 1;

    f32x4 acc[4][4];
    #pragma unroll
    for (int r = 0; r < 4; r++)
        #pragma unroll
        for (int c = 0; c < 4; c++) acc[r][c] = (f32x4){0.f, 0.f, 0.f, 0.f};

    int sr = tid >> 1, sh = (tid & 1) * 32;
    int gm_s = m0 + sr; if (gm_s >= MROWS) gm_s = MROWS - 1;  // clamp, stores guarded
    const size_t arow = (size_t)gm_s * DM;
    const size_t brow = (size_t)(n0 + sr) * DM;

    for (int kc = 0; kc < DM; kc += 64) {
        if (bf) {
            const uint4* src = (const uint4*)((const unsigned short*)X + arow + kc + sh);
            #pragma unroll
            for (int u = 0; u < 4; u++) *(uint4*)&As[sr][sh + u * 8] = src[u];
        } else {
            const float* src = (const float*)X + arow + kc + sh;
            unsigned short tmp[32];
            #pragma unroll
            for (int u = 0; u < 8; u++) {
                float4 f = ((const float4*)src)[u];
                tmp[u*4+0] = f2bu(f.x); tmp[u*4+1] = f2bu(f.y);
                tmp[u*4+2] = f2bu(f.z); tmp[u*4+3] = f2bu(f.w);
            }
            #pragma unroll
            for (int u = 0; u < 4; u++) *(uint4*)&As[sr][sh + u * 8] = *(const uint4*)&tmp[u * 8];
        }
        {
            const uint4* src = (const uint4*)(WT + brow + kc + sh);
            #pragma unroll
            for (int u = 0; u < 4; u++) *(uint4*)&Bs[sr][sh + u * 8] = src[u];
        }
        __syncthreads();
        #pragma unroll
        for (int s = 0; s < 2; s++) {
            short8 af[4], bfr[4];
            #pragma unroll
            for (int r = 0; r < 4; r++)
                af[r] = *(const short8*)&As[wr * 64 + r * 16 + (lane & 15)][s * 32 + (lane >> 4) * 8];
            #pragma unroll
            for (int c = 0; c < 4; c++)
                bfr[c] = *(const short8*)&Bs[wc * 64 + c * 16 + (lane & 15)][s * 32 + (lane >> 4) * 8];
            #pragma unroll
            for (int r = 0; r < 4; r++)
                #pragma unroll
                for (int c = 0; c < 4; c++)
                    acc[r][c] = __builtin_amdgcn_mfma_f32_16x16x32_bf16(af[r], bfr[c], acc[r][c], 0, 0, 0);
        }
        __syncthreads();
    }
    int rbase = (lane >> 4) * 4, cbase = lane & 15;
    #pragma unroll
    for (int r = 0; r < 4; r++) {
        #pragma unroll
        for (int jj = 0; jj < 4; jj++) {
            int gm = m0 + wr * 64 + r * 16 + rbase + jj;
            if (gm < MROWS) {
                int b = gm / SEQ, n = gm % SEQ;
                #pragma unroll
                for (int c = 0; c < 4; c++) {
                    int gc = n0 + wc * 64 + c * 16 + cbase;
                    int h = gc >> 6, d = gc & 63;
                    Y[(((size_t)(b * NH + h) * SEQ) + n) * DK + d] = f2bu(acc[r][c][jj] * scale);
                }
            }
        }
    }
}

// ---------- V transpose: vh (B,H,N,64) -> vt (B,H,64,640) ----------
__global__ __launch_bounds__(256) void k_vt(const unsigned short* __restrict__ vh,
                                            unsigned short* __restrict__ vt) {
    int ntile = blockIdx.x;       // 0..9
    int bh = blockIdx.y;          // 0..191
    __shared__ unsigned short Ts[64][72];
    int tid = threadIdx.x;
    int n0 = ntile * 64;
    {
        int r = tid >> 2, c = (tid & 3) * 16;
        int gn = n0 + r; if (gn > 576) gn = 576;
        const uint4* src = (const uint4*)(vh + ((size_t)bh * SEQ + gn) * DK + c);
        uint4 a = src[0], bv = src[1];
        *(uint4*)&Ts[r][c] = a; *(uint4*)&Ts[r][c + 8] = bv;
    }
    __syncthreads();
    {
        int d = tid >> 2, c = (tid & 3) * 16;
        unsigned short tmp[16];
        #pragma unroll
        for (int u = 0; u < 16; u++) tmp[u] = Ts[c + u][d];
        uint4* dst = (uint4*)(vt + ((size_t)bh * DK + d) * 640 + n0 + c);
        dst[0] = *(uint4*)&tmp[0];
        dst[1] = *(uint4*)&tmp[8];
    }
}

// ---------- flash attention: 512 threads, QBLK=128, 8 waves of 16-row strips ----------
__global__ __launch_bounds__(512, 4) void k_attn2(const unsigned short* __restrict__ qh,
                                                  const unsigned short* __restrict__ kh,
                                                  const unsigned short* __restrict__ vt,
                                                  const float* __restrict__ pen,
                                                  unsigned short* __restrict__ O) {
    // XCD-aware bijective swizzle (960 blocks, 960 % 8 == 0)
    const int NWG = 5 * NH * B_;               // 960
    int flat = blockIdx.x + 5 * (blockIdx.y + NH * blockIdx.z);
    int id = (flat & 7) * (NWG >> 3) + (flat >> 3);
    int it = id % 5; int t2 = id / 5;
    int h = t2 % NH;  int b = t2 / NH;
    int bh = b * NH + h;
    int i0 = it * 128;

    __shared__ __align__(16) unsigned short Qs[128][72];
    __shared__ __align__(16) unsigned short Ks[64][72];
    __shared__ __align__(16) unsigned short Vs[64][72];
    __shared__ __align__(16) unsigned short Ps[128][72];
    int tid = threadIdx.x;
    int lane = tid & 63, w = tid >> 6;          // 8 waves

    // stage Q tile (128 rows, clamp OOB)
    {
        int r = tid >> 2, c = (tid & 3) * 16;
        int gi = i0 + r; if (gi > 576) gi = 576;
        const uint4* src = (const uint4*)(qh + ((size_t)bh * SEQ + gi) * DK + c);
        uint4 a = src[0], bv = src[1];
        *(uint4*)&Qs[r][c] = a; *(uint4*)&Qs[r][c + 8] = bv;
    }
    __syncthreads();
    short8 qfrag[2];
    #pragma unroll
    for (int s = 0; s < 2; s++)
        qfrag[s] = *(const short8*)&Qs[w * 16 + (lane & 15)][s * 32 + (lane >> 4) * 8];

    f32x4 o_acc[4];
    #pragma unroll
    for (int i = 0; i < 4; i++) o_acc[i] = (f32x4){0.f, 0.f, 0.f, 0.f};
    float m_run[4], l_run[4];
    #pragma unroll
    for (int r = 0; r < 4; r++) { m_run[r] = -1e30f; l_run[r] = 0.f; }

    const float* penb = pen + (size_t)b * P_ * P_;
    int colbase = lane & 15;
    int rloc = (lane >> 4) * 4;

    // per-row validity + clamped pen row pointers (loop-invariant)
    const float* prow[4]; bool iok[4];
    #pragma unroll
    for (int rg = 0; rg < 4; rg++) {
        int i = i0 + w * 16 + rloc + rg;
        int ii = i < 1 ? 1 : (i > 576 ? 576 : i);
        prow[rg] = penb + (size_t)(ii - 1) * P_;
        iok[rg] = (i >= 1 && i <= 576);
    }

    for (int kt = 0; kt < 10; kt++) {
        int j0 = kt * 64;
        // stage K tile (64x64) and V tile (64 dims x 64 keys); 1 uint4 each per thread
        {
            int r = tid >> 3, c = (tid & 7) * 8;
            int gj = j0 + r; if (gj > 576) gj = 576;
            *(uint4*)&Ks[r][c] = *(const uint4*)(kh + ((size_t)bh * SEQ + gj) * DK + c);
            *(uint4*)&Vs[r][c] = *(const uint4*)(vt + ((size_t)bh * DK + r) * 640 + j0 + c);
        }
        __syncthreads();

        // prefetch penalty (independent of S) — loads overlap the MFMAs below
        float pf[4][4];
        #pragma unroll
        for (int rg = 0; rg < 4; rg++) {
            #pragma unroll
            for (int nt = 0; nt < 4; nt++) {
                int j = j0 + nt * 16 + colbase;
                int jj = j < 1 ? 1 : (j > 576 ? 576 : j);
                float pv = prow[rg][jj - 1];
                pf[rg][nt] = (iok[rg] && j >= 1 && j <= 576) ? pv : 0.f;
            }
        }

        // S = Q K^T (wave strip: 16 rows x 64 keys)
        f32x4 sfrag[4];
        __builtin_amdgcn_s_setprio(1);
        #pragma unroll
        for (int nt = 0; nt < 4; nt++) {
            f32x4 acc = (f32x4){0.f, 0.f, 0.f, 0.f};
            #pragma unroll
            for (int s = 0; s < 2; s++) {
                short8 bfrag = *(const short8*)&Ks[nt * 16 + colbase][s * 32 + (lane >> 4) * 8];
                acc = __builtin_amdgcn_mfma_f32_16x16x32_bf16(qfrag[s], bfrag, acc, 0, 0, 0);
            }
            sfrag[nt] = acc;
        }
        __builtin_amdgcn_s_setprio(0);

        // apply penalty + key mask
        #pragma unroll
        for (int nt = 0; nt < 4; nt++) {
            int j = j0 + nt * 16 + colbase;
            #pragma unroll
            for (int rg = 0; rg < 4; rg++) {
                float sv = sfrag[nt][rg] - pf[rg][nt];
                if (j > 576) sv = -1e30f;
                sfrag[nt][rg] = sv;
            }
        }
        // online softmax (rows live across 16 lanes of each quad-group)
        float alpha[4];
        #pragma unroll
        for (int rg = 0; rg < 4; rg++) {
            float t = fmaxf(fmaxf(sfrag[0][rg], sfrag[1][rg]),
                            fmaxf(sfrag[2][rg], sfrag[3][rg]));
            #pragma unroll
            for (int off = 1; off < 16; off <<= 1) t = fmaxf(t, __shfl_xor(t, off, 64));
            float mn = fmaxf(m_run[rg], t);
            alpha[rg] = __expf(m_run[rg] - mn);
            m_run[rg] = mn;
        }
        float rsum[4] = {0.f, 0.f, 0.f, 0.f};
        #pragma unroll
        for (int nt = 0; nt < 4; nt++) {
            #pragma unroll
            for (int rg = 0; rg < 4; rg++) {
                float p = __expf(sfrag[nt][rg] - m_run[rg]);
                rsum[rg] += p;
                Ps[w * 16 + rloc + rg][nt * 16 + colbase] = f2bu(p);
            }
        }
        #pragma unroll
        for (int rg = 0; rg < 4; rg++) {
            float t = rsum[rg];
            #pragma unroll
            for (int off = 1; off < 16; off <<= 1) t += __shfl_xor(t, off, 64);
            l_run[rg] = l_run[rg] * alpha[rg] + t;
        }
        #pragma unroll
        for (int nt = 0; nt < 4; nt++)
            #pragma unroll
            for (int rg = 0; rg < 4; rg++) o_acc[nt][rg] *= alpha[rg];

        // O += P V
        __builtin_amdgcn_s_setprio(1);
        #pragma unroll
        for (int s = 0; s < 2; s++) {
            short8 afrag = *(const short8*)&Ps[w * 16 + (lane & 15)][s * 32 + (lane >> 4) * 8];
            #pragma unroll
            for (int nt = 0; nt < 4; nt++) {
                short8 bfrag = *(const short8*)&Vs[nt * 16 + colbase][s * 32 + (lane >> 4) * 8];
                o_acc[nt] = __builtin_amdgcn_mfma_f32_16x16x32_bf16(afrag, bfrag, o_acc[nt], 0, 0, 0);
            }
        }
        __builtin_amdgcn_s_setprio(0);
        __syncthreads();
    }
    // normalize + store bf16 (O layout: (b, n, h, d) == row-major (9232, 768))
    #pragma unroll
    for (int rg = 0; rg < 4; rg++) {
        int i = i0 + w * 16 + rloc + rg;
        if (i < SEQ) {
            float linv = 1.0f / l_run[rg];
            #pragma unroll
            for (int nt = 0; nt < 4; nt++) {
                int d = nt * 16 + colbase;
                O[(((size_t)(b * SEQ + i)) * NH + h) * DK + d] = f2bu(o_acc[nt][rg] * linv);
            }
        }
    }
}

// ---------- out projection via MFMA + residual: fc = Obf @ wfc + q ----------
// 1-D grid 438, serial = (m, n) with n innermost; XCD-chunked (r=6 bijective).
__global__ __launch_bounds__(256) void k_fc_mfma(const unsigned short* __restrict__ Obf,
                                                 const unsigned short* __restrict__ wtfc,
                                                 const void* __restrict__ qin,
                                                 const void* __restrict__ gamma,
                                                 float* __restrict__ fcout) {
    bool bf = bf_flag(gamma);
    int p = xcd_chunk(blockIdx.x, 73 * 6);
    int m0 = (p / 6) * 128, n0 = (p % 6) * 128;
    __shared__ __align__(16) unsigned short As[128][72];
    __shared__ __align__(16) unsigned short Bs[128][72];
    int tid = threadIdx.x;
    int lane = tid & 63, w = tid >> 6;
    int wr = w >> 1, wc = w & 1;

    f32x4 acc[4][4];
    #pragma unroll
    for (int r = 0; r < 4; r++)
        #pragma unroll
        for (int c = 0; c < 4; c++) acc[r][c] = (f32x4){0.f, 0.f, 0.f, 0.f};

    int sr = tid >> 1, sh = (tid & 1) * 32;
    int gm_s = m0 + sr; if (gm_s >= MROWS) gm_s = MROWS - 1;
    const size_t arow = (size_t)gm_s * DM;
    const size_t brow = (size_t)(n0 + sr) * DM;

    for (int kc = 0; kc < DM; kc += 64) {
        {
            const uint4* src = (const uint4*)(Obf + arow + kc + sh);
            #pragma unroll
            for (int u = 0; u < 4; u++) *(uint4*)&As[sr][sh + u * 8] = src[u];
        }
        {
            const uint4* src = (const uint4*)(wtfc + brow + kc + sh);
            #pragma unroll
            for (int u = 0; u < 4; u++) *(uint4*)&Bs[sr][sh + u * 8] = src[u];
        }
        __syncthreads();
        #pragma unroll
        for (int s = 0; s < 2; s++) {
            short8 af[4], bfr[4];
            #pragma unroll
            for (int r = 0; r < 4; r++)
                af[r] = *(const short8*)&As[wr * 64 + r * 16 + (lane & 15)][s * 32 + (lane >> 4) * 8];
            #pragma unroll
            for (int c = 0; c < 4; c++)
                bfr[c] = *(const short8*)&Bs[wc * 64 + c * 16 + (lane & 15)][s * 32 + (lane >> 4) * 8];
            #pragma unroll
            for (int r = 0; r < 4; r++)
                #pragma unroll
                for (int c = 0; c < 4; c++)
                    acc[r][c] = __builtin_amdgcn_mfma_f32_16x16x32_bf16(af[r], bfr[c], acc[r][c], 0, 0, 0);
        }
        __syncthreads();
    }
    int rbase = (lane >> 4) * 4, cbase = lane & 15;
    #pragma unroll
    for (int r = 0; r < 4; r++) {
        #pragma unroll
        for (int jj = 0; jj < 4; jj++) {
            int gm = m0 + wr * 64 + r * 16 + rbase + jj;
            if (gm < MROWS) {
                #pragma unroll
                for (int c = 0; c < 4; c++) {
                    int gc = n0 + wc * 64 + c * 16 + cbase;
                    fcout[(size_t)gm * DM + gc] = acc[r][c][jj] + ldf(qin, (size_t)gm * DM + gc, bf);
                }
            }
        }
    }
}

// ---------- layernorm (dtype-adaptive output) ----------
__global__ __launch_bounds__(256) void k_ln(const float* __restrict__ x,
                                            const void* __restrict__ gamma,
                                            const void* __restrict__ beta,
                                            void* __restrict__ out) {
    bool bf = bf_flag(gamma);
    int row = blockIdx.x;
    const float* xr = x + (size_t)row * DM;
    int tid = threadIdx.x;
    float v[3];
    float ssum = 0.f;
    #pragma unroll
    for (int u = 0; u < 3; u++) { v[u] = xr[tid + u * 256]; ssum += v[u]; }
    __shared__ float red[4];
    __shared__ float mu_s, var_s;
    float t = ssum;
    for (int off = 32; off > 0; off >>= 1) t += __shfl_down(t, off, 64);
    int lane = tid & 63, w = tid >> 6;
    if (lane == 0) red[w] = t;
    __syncthreads();
    if (tid == 0) mu_s = (red[0] + red[1] + red[2] + red[3]) * (1.0f / DM);
    __syncthreads();
    float mu = mu_s;
    float vs = 0.f;
    #pragma unroll
    for (int u = 0; u < 3; u++) { float d = v[u] - mu; vs += d * d; }
    t = vs;
    for (int off = 32; off > 0; off >>= 1) t += __shfl_down(t, off, 64);
    if (lane == 0) red[w] = t;
    __syncthreads();
    if (tid == 0) var_s = (red[0] + red[1] + red[2] + red[3]) * (1.0f / DM);
    __syncthreads();
    float rstd = rsqrtf(var_s + LNEPS);
    #pragma unroll
    for (int u = 0; u < 3; u++) {
        int c = tid + u * 256;
        float val = (v[u] - mu) * rstd * ldf(gamma, c, bf) + ldf(beta, c, bf);
        size_t idx = (size_t)row * DM + c;
        if (bf) ((__hip_bfloat16*)out)[idx] = __float2bfloat16(val);
        else    ((float*)out)[idx] = val;
    }
}

extern "C" void kernel_launch(void* const* d_in, const int* in_sizes, int n_in,
                              void* d_out, int out_size, void* d_ws, size_t ws_size,
                              hipStream_t stream) {
    const void* q   = d_in[0];
    const void* k   = d_in[1];
    const void* v   = d_in[2];
    const void* pos = d_in[3];
    const void* pe  = d_in[4];
    const void* wq  = d_in[5];
    const void* wk  = d_in[6];
    const void* wv  = d_in[7];
    const void* wfc = d_in[8];
    const void* gam = d_in[9];
    const void* bet = d_in[10];
    char* wsb = (char*)d_ws;
    float*          pen = (float*)(wsb + PEN_B);
    unsigned short* qh  = (unsigned short*)(wsb + QH_B);
    unsigned short* kh  = (unsigned short*)(wsb + KH_B);
    unsigned short* vh  = (unsigned short*)(wsb + VH_B);
    unsigned short* vt  = (unsigned short*)(wsb + VT_B);
    unsigned short* Obf = (unsigned short*)(wsb + OBF_B);
    unsigned short* wt  = (unsigned short*)(wsb + WT_B);
    float*          rn  = (float*)(wsb + RN_B);
    float*          fc  = (float*)(wsb + FC_B);

    k_wt<<<dim3(12, 12, 4), 256, 0, stream>>>(wq, wk, wv, wfc, gam, wt);
    k_rownorm<<<B_ * P_, 256, 0, stream>>>(pe, gam, rn);
    k_penalty_mfma<<<dim3(9 * 9 * B_), 256, 0, stream>>>(pe, pos, gam, rn, pen);
    k_proj_mfma<<<dim3(73 * 6 * 3), 256, 0, stream>>>(q, k, v, wt, gam, qh, kh, vh);
    k_vt<<<dim3(10, 192), 256, 0, stream>>>(vh, vt);
    k_attn2<<<dim3(5, NH, B_), 512, 0, stream>>>(qh, kh, vt, pen, Obf);
    k_fc_mfma<<<dim3(73 * 6), 256, 0, stream>>>(Obf, wt + (size_t)3 * DM * DM, q, gam, fc);
    k_ln<<<MROWS, 256, 0, stream>>>(fc, gam, bet, d_out);
}